// Round 2
// baseline (747.110 us; speedup 1.0000x reference)
//
#include <hip/hip_runtime.h>
#include <math.h>

#define BATCH 16
#define P 32768
#define C 81
#define CM1 80
#define NCAND 400
#define NOUT 100
#define NBINS 512
#define SMIN_F (-8.0f)
#define BIN_SCALE 64.0f
#define CAND_MAX 4096
#define SORTN 2048
#define IMG_SZ 512.0f
#define NMS_THR 0.45f
#define NWORDS 7
#define NPAD 448

#define ROWS_PER_BLOCK 512
#define ROWS_PER_WAVE 128

// ---- workspace layout (bytes) ----
#define OFF_HIST 0                                  // BATCH*NBINS*4 = 32768
#define OFF_CNT  (OFF_HIST + BATCH * NBINS * 4)     // 64
#define OFF_CVAL (OFF_CNT + 64)                     // BATCH*CAND_MAX*4
#define OFF_CIDX (OFF_CVAL + BATCH * CAND_MAX * 4)  // BATCH*CAND_MAX*4

__device__ __forceinline__ int score_bin(float sc) {
    int b = (int)((sc - SMIN_F) * BIN_SCALE);
    return b < 0 ? 0 : (b > NBINS - 1 ? NBINS - 1 : b);
}

// wave-per-row logsumexp: lane l holds col l and col 64+l (l<17).
// Returns sc1 (col=lane) and sc2 (col=64+lane); identical arithmetic in both passes.
__device__ __forceinline__ void row_scores(const float* __restrict__ row, int lane,
                                           float& sc1, float& sc2) {
    float v1 = row[lane];
    float v2 = (lane < C - 64) ? row[64 + lane] : -INFINITY;
    float m = fmaxf(v1, v2);
#pragma unroll
    for (int off = 32; off >= 1; off >>= 1) m = fmaxf(m, __shfl_xor(m, off));
    float s = expf(v1 - m) + ((lane < C - 64) ? expf(v2 - m) : 0.0f);
#pragma unroll
    for (int off = 32; off >= 1; off >>= 1) s += __shfl_xor(s, off);
    float l = logf(s);
    sc1 = v1 - m - l;
    sc2 = v2 - m - l;
}

__global__ __launch_bounds__(256) void k_hist(const float* __restrict__ logits,
                                              unsigned* __restrict__ hist) {
    __shared__ unsigned lh[NBINS];
    for (int b = threadIdx.x; b < NBINS; b += 256) lh[b] = 0;
    __syncthreads();
    int img = blockIdx.y;
    int lane = threadIdx.x & 63;
    int wv = threadIdx.x >> 6;
    const float* base = logits + (size_t)img * P * C;
    int p0 = blockIdx.x * ROWS_PER_BLOCK + wv * ROWS_PER_WAVE;
    for (int r = 0; r < ROWS_PER_WAVE; ++r) {
        int p = p0 + r;
        float sc1, sc2;
        row_scores(base + (size_t)p * C, lane, sc1, sc2);
        if (lane >= 1 && sc1 > SMIN_F) atomicAdd(&lh[score_bin(sc1)], 1u);
        if (lane < C - 64 && sc2 > SMIN_F) atomicAdd(&lh[score_bin(sc2)], 1u);
    }
    __syncthreads();
    unsigned* gh = hist + (size_t)img * NBINS;
    for (int b = threadIdx.x; b < NBINS; b += 256)
        if (lh[b]) atomicAdd(&gh[b], lh[b]);
}

__global__ __launch_bounds__(256) void k_collect(const float* __restrict__ logits,
                                                 const unsigned* __restrict__ hist,
                                                 unsigned* __restrict__ cnt,
                                                 float* __restrict__ cval,
                                                 unsigned* __restrict__ cidx) {
    __shared__ unsigned lhist[NBINS];
    __shared__ int thr_sh;
    int img = blockIdx.y;
    for (int b = threadIdx.x; b < NBINS; b += 256) lhist[b] = hist[(size_t)img * NBINS + b];
    __syncthreads();
    if (threadIdx.x == 0) {
        unsigned cum = 0;
        int b = NBINS - 1;
        for (; b >= 0; --b) {
            cum += lhist[b];
            if (cum >= NCAND) break;
        }
        thr_sh = b < 0 ? 0 : b;
    }
    __syncthreads();
    int tb = thr_sh;
    int lane = threadIdx.x & 63;
    int wv = threadIdx.x >> 6;
    const float* base = logits + (size_t)img * P * C;
    int p0 = blockIdx.x * ROWS_PER_BLOCK + wv * ROWS_PER_WAVE;
    for (int r = 0; r < ROWS_PER_WAVE; ++r) {
        int p = p0 + r;
        float sc1, sc2;
        row_scores(base + (size_t)p * C, lane, sc1, sc2);
        if (lane >= 1 && sc1 > SMIN_F && score_bin(sc1) >= tb) {
            unsigned pos = atomicAdd(&cnt[img], 1u);
            if (pos < CAND_MAX) {
                cval[(size_t)img * CAND_MAX + pos] = sc1;
                cidx[(size_t)img * CAND_MAX + pos] = (unsigned)(p * CM1 + lane - 1);
            }
        }
        if (lane < C - 64 && sc2 > SMIN_F && score_bin(sc2) >= tb) {
            unsigned pos = atomicAdd(&cnt[img], 1u);
            if (pos < CAND_MAX) {
                cval[(size_t)img * CAND_MAX + pos] = sc2;
                cidx[(size_t)img * CAND_MAX + pos] = (unsigned)(p * CM1 + 63 + lane);
            }
        }
    }
}

__global__ __launch_bounds__(1024) void k_nms(const float* __restrict__ bbox,
                                              const float* __restrict__ priors,
                                              const unsigned* __restrict__ cnt,
                                              const float* __restrict__ cval,
                                              const unsigned* __restrict__ cidx,
                                              float* __restrict__ out) {
    __shared__ float v[SORTN];
    __shared__ unsigned ix[SORTN];
    __shared__ float x1[NCAND], y1[NCAND], x2[NCAND], y2[NCAND];
    __shared__ float ox1[NPAD], oy1[NPAD], ox2[NPAD], oy2[NPAD], areas[NPAD];
    __shared__ float scs[NCAND];
    __shared__ int lab[NCAND];
    __shared__ unsigned long long M[NCAND][NWORDS];
    __shared__ unsigned long long keepw_s[NWORDS];
    __shared__ int wpre_s[NWORDS + 1];
    __shared__ float wred[16];
    __shared__ float maxc_sh;
    __shared__ int kidx[NOUT];

    int img = blockIdx.x;
    int tid = threadIdx.x;
    int lane = tid & 63;
    int wv = tid >> 6;

    // ---- load candidates ----
    unsigned n = cnt[img];
    if (n > SORTN) n = SORTN;
    for (int i = tid; i < SORTN; i += 1024) {
        if ((unsigned)i < n) {
            v[i] = cval[(size_t)img * CAND_MAX + i];
            ix[i] = cidx[(size_t)img * CAND_MAX + i];
        } else {
            v[i] = -INFINITY;
            ix[i] = 0x7FFFFFFFu;
        }
    }
    __syncthreads();

    // ---- bitonic sort: descending value, ascending index on ties ----
    for (int k = 2; k <= SORTN; k <<= 1) {
        for (int j = k >> 1; j > 0; j >>= 1) {
            for (int t = tid; t < SORTN; t += 1024) {
                int l = t ^ j;
                if (l > t) {
                    float va = v[t], vb = v[l];
                    unsigned ia = ix[t], ib = ix[l];
                    bool b_first = (vb > va) || (vb == va && ib < ia);
                    bool a_first = (va > vb) || (va == vb && ia < ib);
                    bool dir = ((t & k) == 0);
                    bool sw = dir ? b_first : a_first;
                    if (sw) { v[t] = vb; v[l] = va; ix[t] = ib; ix[l] = ia; }
                }
            }
            __syncthreads();
        }
    }

    // ---- decode top-400 ----
    if (tid < NCAND) {
        unsigned f = ix[tid];
        if (f > (unsigned)(P * CM1 - 1)) f = (unsigned)(P * CM1 - 1);  // safety
        int p = (int)(f / CM1);
        int c = (int)(f % CM1) + 1;
        const float* lp = bbox + ((size_t)img * P + p) * 4;
        const float* pp = priors + (size_t)p * 4;
        float cx = lp[0] * 0.1f * pp[2] + pp[0];
        float cy = lp[1] * 0.1f * pp[3] + pp[1];
        float w = expf(lp[2] * 0.2f) * pp[2];
        float h = expf(lp[3] * 0.2f) * pp[3];
        x1[tid] = (cx - w * 0.5f) * IMG_SZ;
        y1[tid] = (cy - h * 0.5f) * IMG_SZ;
        x2[tid] = (cx + w * 0.5f) * IMG_SZ;
        y2[tid] = (cy + h * 0.5f) * IMG_SZ;
        scs[tid] = v[tid];
        lab[tid] = c;
    }
    __syncthreads();

    // ---- max coordinate ----
    float m = -INFINITY;
    if (tid < NCAND)
        m = fmaxf(fmaxf(x1[tid], y1[tid]), fmaxf(x2[tid], y2[tid]));
#pragma unroll
    for (int off = 32; off >= 1; off >>= 1) m = fmaxf(m, __shfl_xor(m, off));
    if (lane == 0) wred[wv] = m;
    __syncthreads();
    if (tid == 0) {
        float mm = -INFINITY;
        for (int t = 0; t < 16; ++t) mm = fmaxf(mm, wred[t]);
        maxc_sh = mm;
    }
    __syncthreads();

    // ---- class offsets (+pad) ----
    if (tid < NPAD) {
        if (tid < NCAND) {
            float off = (float)lab[tid] * (maxc_sh + 1.0f);
            ox1[tid] = x1[tid] + off;
            oy1[tid] = y1[tid] + off;
            ox2[tid] = x2[tid] + off;
            oy2[tid] = y2[tid] + off;
            areas[tid] = (ox2[tid] - ox1[tid]) * (oy2[tid] - oy1[tid]);
        } else {
            ox1[tid] = 1e30f; oy1[tid] = 1e30f;
            ox2[tid] = 1e30f; oy2[tid] = 1e30f;
            areas[tid] = 0.0f;
        }
    }
    __syncthreads();

    // ---- IoU mask: wave per row, ballot forms the 64-bit words ----
    for (int i = wv; i < NCAND; i += 16) {
        float a1 = ox1[i], b1 = oy1[i], a2 = ox2[i], b2 = oy2[i], ar = areas[i];
#pragma unroll
        for (int wd = 0; wd < NWORDS; ++wd) {
            int j = wd * 64 + lane;
            float ltx = fmaxf(a1, ox1[j]);
            float lty = fmaxf(b1, oy1[j]);
            float rbx = fminf(a2, ox2[j]);
            float rby = fminf(b2, oy2[j]);
            float iw = fmaxf(rbx - ltx, 0.0f);
            float ih = fmaxf(rby - lty, 0.0f);
            float inter = iw * ih;
            float uni = ar + areas[j] - inter;
            float iou = inter / fmaxf(uni, 1e-12f);
            unsigned long long bits = __ballot(iou > NMS_THR);
            if (lane == 0) M[i][wd] = bits;
        }
    }
    __syncthreads();

    // ---- greedy NMS: keep words in registers (pure-ALU chain) ----
    if (tid == 0) {
        unsigned long long kw[NWORDS];
#pragma unroll
        for (int w = 0; w < NWORDS - 1; ++w) kw[w] = ~0ull;
        kw[NWORDS - 1] = (1ull << (NCAND - 64 * (NWORDS - 1))) - 1ull;
        for (int i = 0; i < NCAND; ++i) {
            int iw = i >> 6, ib = i & 63;
            if ((kw[iw] >> ib) & 1ull) {
#pragma unroll
                for (int w = 0; w < NWORDS; ++w) {
                    if (w > iw) kw[w] &= ~M[i][w];
                    else if (w == iw && ib != 63)
                        kw[w] &= ~(M[i][w] & (~0ull << (ib + 1)));
                }
            }
        }
        int acc = 0;
#pragma unroll
        for (int w = 0; w < NWORDS; ++w) {
            keepw_s[w] = kw[w];
            wpre_s[w] = acc;
            acc += __popcll(kw[w]);
        }
        wpre_s[NWORDS] = acc;
    }
    __syncthreads();

    // ---- kidx: kept (ascending) first, then unkept (ascending) ----
    if (tid < NCAND) {
        int w = tid >> 6, b = tid & 63;
        unsigned long long kwv = keepw_s[w];
        bool kp = (kwv >> b) & 1ull;
        unsigned long long below_mask = (b == 0) ? 0ull : (~0ull >> (64 - b));
        int below = wpre_s[w] + __popcll(kwv & below_mask);
        int nkept = wpre_s[NWORDS];
        int pos = kp ? below : nkept + (tid - below);
        if (pos < NOUT) kidx[pos] = tid;
    }
    __syncthreads();

    // ---- outputs: boxes [16,100,4] | labels [16,100] | scores [16,100] ----
    if (tid < NOUT) {
        int i = kidx[tid];
        bool kp = (keepw_s[i >> 6] >> (i & 63)) & 1ull;
        float* ob = out + ((size_t)img * NOUT + tid) * 4;
        ob[0] = x1[i];
        ob[1] = y1[i];
        ob[2] = x2[i];
        ob[3] = y2[i];
        out[(size_t)BATCH * NOUT * 4 + (size_t)img * NOUT + tid] = (float)lab[i];
        out[(size_t)BATCH * NOUT * 4 + (size_t)BATCH * NOUT + (size_t)img * NOUT + tid] =
            kp ? scs[i] : -INFINITY;
    }
}

extern "C" void kernel_launch(void* const* d_in, const int* in_sizes, int n_in,
                              void* d_out, int out_size, void* d_ws, size_t ws_size,
                              hipStream_t stream) {
    const float* logits = (const float*)d_in[0];
    const float* bbox = (const float*)d_in[1];
    const float* priors = (const float*)d_in[2];
    float* out = (float*)d_out;
    char* ws = (char*)d_ws;

    unsigned* hist = (unsigned*)(ws + OFF_HIST);
    unsigned* cnt = (unsigned*)(ws + OFF_CNT);
    float* cval = (float*)(ws + OFF_CVAL);
    unsigned* cidx = (unsigned*)(ws + OFF_CIDX);

    hipMemsetAsync(ws, 0, OFF_CVAL, stream);  // zero hist + cnt

    dim3 grid(P / ROWS_PER_BLOCK, BATCH);
    k_hist<<<grid, 256, 0, stream>>>(logits, hist);
    k_collect<<<grid, 256, 0, stream>>>(logits, hist, cnt, cval, cidx);
    k_nms<<<BATCH, 1024, 0, stream>>>(bbox, priors, cnt, cval, cidx, out);
}

// Round 3
// 500.847 us; speedup vs baseline: 1.4917x; 1.4917x over previous
//
#include <hip/hip_runtime.h>
#include <math.h>

#define BATCH 16
#define P 32768
#define C 81
#define CM1 80
#define NCAND 400
#define NOUT 100
#define NBINS 256
#define SMIN_F (-3.0f)
#define BIN_SCALE (NBINS / 3.0f)
#define CAND_MAX 4096
#define SORTN 1024
#define IMG_SZ 512.0f
#define NMS_THR 0.45f
#define NWORDS 7
#define NPAD 448
#define TROWS 64

// ---- workspace layout (bytes) ----
#define OFF_HIST 0                                   // BATCH*NBINS*4 = 16384
#define OFF_CNT  (OFF_HIST + BATCH * NBINS * 4)      // 64
#define OFF_THR  (OFF_CNT + 64)                      // 64
#define OFF_CVAL (OFF_THR + 64)                      // BATCH*CAND_MAX*4 = 262144
#define OFF_CIDX (OFF_CVAL + BATCH * CAND_MAX * 4)   // 262144
#define OFF_MAXSC (OFF_CIDX + BATCH * CAND_MAX * 4)  // BATCH*P*4 = 2097152
#define NEED_FAST (OFF_MAXSC + (size_t)BATCH * P * 4)

__device__ __forceinline__ int score_bin(float sc) {
    int b = (int)((sc - SMIN_F) * BIN_SCALE);
    return b < 0 ? 0 : (b > NBINS - 1 ? NBINS - 1 : b);
}

// Serial per-row stats; MUST be arithmetically identical everywhere it's used.
__device__ __forceinline__ void row_stats(const float r[C], float& m, float& l) {
    float mm = r[0];
#pragma unroll
    for (int c = 1; c < C; ++c) mm = fmaxf(mm, r[c]);
    float s = 0.0f;
#pragma unroll
    for (int c = 0; c < C; ++c) s += __expf(r[c] - mm);
    m = mm;
    l = __logf(s);
}

// ---- pass 1: coalesced LDS staging, per-thread row, histogram + row max score ----
__global__ __launch_bounds__(TROWS) void k_hist(const float* __restrict__ logits,
                                                unsigned* __restrict__ hist,
                                                float* __restrict__ maxsc,
                                                int write_maxsc) {
    __shared__ float tile[TROWS * C];  // 20736 B
    __shared__ unsigned lh[NBINS];
    int img = blockIdx.y;
    int row0 = blockIdx.x * TROWS;
    for (int b = threadIdx.x; b < NBINS; b += TROWS) lh[b] = 0;
    const float4* g4 = (const float4*)(logits + ((size_t)img * P + row0) * C);
    float4* t4 = (float4*)tile;
    for (int k = threadIdx.x; k < TROWS * C / 4; k += TROWS) t4[k] = g4[k];
    __syncthreads();
    float r[C];
    const float* rowp = tile + threadIdx.x * C;
#pragma unroll
    for (int c = 0; c < C; ++c) r[c] = rowp[c];
    float m, l;
    row_stats(r, m, l);
    float mx = r[1];
#pragma unroll
    for (int c = 2; c < C; ++c) mx = fmaxf(mx, r[c]);
    if (write_maxsc) maxsc[(size_t)img * P + row0 + threadIdx.x] = (mx - m) - l;
#pragma unroll
    for (int c = 1; c < C; ++c) {
        float sc = (r[c] - m) - l;
        if (sc > SMIN_F) atomicAdd(&lh[score_bin(sc)], 1u);
    }
    __syncthreads();
    unsigned* gh = hist + (size_t)img * NBINS;
    for (int b = threadIdx.x; b < NBINS; b += TROWS)
        if (lh[b]) atomicAdd(&gh[b], lh[b]);
}

__global__ void k_thresh(const unsigned* __restrict__ hist, unsigned* __restrict__ thr) {
    __shared__ unsigned lh[NBINS];
    int img = blockIdx.x;
    for (int b = threadIdx.x; b < NBINS; b += blockDim.x)
        lh[b] = hist[(size_t)img * NBINS + b];
    __syncthreads();
    if (threadIdx.x == 0) {
        unsigned cum = 0;
        int b = NBINS - 1;
        for (; b >= 0; --b) {
            cum += lh[b];
            if (cum >= NCAND) break;
        }
        thr[img] = (unsigned)(b < 0 ? 0 : b);
    }
}

// ---- pass 2 (fast): row filter via maxsc, sparse re-read of qualifying rows ----
__global__ __launch_bounds__(256) void k_collect_fast(const float* __restrict__ logits,
                                                      const float* __restrict__ maxsc,
                                                      const unsigned* __restrict__ thr,
                                                      unsigned* __restrict__ cnt,
                                                      float* __restrict__ cval,
                                                      unsigned* __restrict__ cidx) {
    int img = blockIdx.y;
    int row = blockIdx.x * 256 + threadIdx.x;
    int tb = (int)thr[img];
    float ms = maxsc[(size_t)img * P + row];
    if (!(ms > SMIN_F && score_bin(ms) >= tb)) return;
    const float* rp = logits + ((size_t)img * P + row) * C;
    float r[C];
#pragma unroll
    for (int c = 0; c < C; ++c) r[c] = rp[c];
    float m, l;
    row_stats(r, m, l);
#pragma unroll
    for (int c = 1; c < C; ++c) {
        float sc = (r[c] - m) - l;
        if (sc > SMIN_F && score_bin(sc) >= tb) {
            unsigned pos = atomicAdd(&cnt[img], 1u);
            if (pos < CAND_MAX) {
                cval[(size_t)img * CAND_MAX + pos] = sc;
                cidx[(size_t)img * CAND_MAX + pos] = (unsigned)(row * CM1 + c - 1);
            }
        }
    }
}

// ---- pass 2 (fallback, if ws too small for maxsc): full staged re-scan ----
__global__ __launch_bounds__(TROWS) void k_collect_full(const float* __restrict__ logits,
                                                        const unsigned* __restrict__ thr,
                                                        unsigned* __restrict__ cnt,
                                                        float* __restrict__ cval,
                                                        unsigned* __restrict__ cidx) {
    __shared__ float tile[TROWS * C];
    int img = blockIdx.y;
    int row0 = blockIdx.x * TROWS;
    int tb = (int)thr[img];
    const float4* g4 = (const float4*)(logits + ((size_t)img * P + row0) * C);
    float4* t4 = (float4*)tile;
    for (int k = threadIdx.x; k < TROWS * C / 4; k += TROWS) t4[k] = g4[k];
    __syncthreads();
    float r[C];
    const float* rowp = tile + threadIdx.x * C;
#pragma unroll
    for (int c = 0; c < C; ++c) r[c] = rowp[c];
    float m, l;
    row_stats(r, m, l);
    int row = row0 + threadIdx.x;
#pragma unroll
    for (int c = 1; c < C; ++c) {
        float sc = (r[c] - m) - l;
        if (sc > SMIN_F && score_bin(sc) >= tb) {
            unsigned pos = atomicAdd(&cnt[img], 1u);
            if (pos < CAND_MAX) {
                cval[(size_t)img * CAND_MAX + pos] = sc;
                cidx[(size_t)img * CAND_MAX + pos] = (unsigned)(row * CM1 + c - 1);
            }
        }
    }
}

__device__ __forceinline__ unsigned long long rdlane64(unsigned long long v, int lane) {
    int lo = __builtin_amdgcn_readlane((int)(unsigned)v, lane);
    int hi = __builtin_amdgcn_readlane((int)(unsigned)(v >> 32), lane);
    return ((unsigned long long)(unsigned)hi << 32) | (unsigned)lo;
}

__global__ __launch_bounds__(512) void k_nms(const float* __restrict__ bbox,
                                             const float* __restrict__ priors,
                                             const unsigned* __restrict__ cnt,
                                             const float* __restrict__ cval,
                                             const unsigned* __restrict__ cidx,
                                             float* __restrict__ out) {
    __shared__ float v[SORTN];
    __shared__ unsigned ix[SORTN];
    __shared__ float x1[NCAND], y1[NCAND], x2[NCAND], y2[NCAND];
    __shared__ float ox1[NPAD], oy1[NPAD], ox2[NPAD], oy2[NPAD], areas[NPAD];
    __shared__ float scs[NCAND];
    __shared__ int lab[NCAND];
    __shared__ unsigned long long M[NPAD][NWORDS];
    __shared__ unsigned long long keepw_s[NWORDS];
    __shared__ int wpre_s[NWORDS + 1];
    __shared__ float wred[8];
    __shared__ float maxc_sh;
    __shared__ int kidx[NOUT];

    int img = blockIdx.x;
    int tid = threadIdx.x;
    int lane = tid & 63;
    int wv = tid >> 6;

    unsigned n = cnt[img];
    if (n > SORTN) n = SORTN;
    for (int i = tid; i < SORTN; i += 512) {
        if ((unsigned)i < n) {
            v[i] = cval[(size_t)img * CAND_MAX + i];
            ix[i] = cidx[(size_t)img * CAND_MAX + i];
        } else {
            v[i] = -INFINITY;
            ix[i] = 0x7FFFFFFFu;
        }
    }
    __syncthreads();

    // bitonic sort: descending value, ascending index on ties
    for (int k = 2; k <= SORTN; k <<= 1) {
        for (int j = k >> 1; j > 0; j >>= 1) {
            for (int t = tid; t < SORTN; t += 512) {
                int l = t ^ j;
                if (l > t) {
                    float va = v[t], vb = v[l];
                    unsigned ia = ix[t], ib = ix[l];
                    bool b_first = (vb > va) || (vb == va && ib < ia);
                    bool a_first = (va > vb) || (va == vb && ia < ib);
                    bool sw = ((t & k) == 0) ? b_first : a_first;
                    if (sw) { v[t] = vb; v[l] = va; ix[t] = ib; ix[l] = ia; }
                }
            }
            __syncthreads();
        }
    }

    // decode top-400
    if (tid < NCAND) {
        unsigned f = ix[tid];
        if (f > (unsigned)(P * CM1 - 1)) f = (unsigned)(P * CM1 - 1);
        int p = (int)(f / CM1);
        int c = (int)(f % CM1) + 1;
        const float* lp = bbox + ((size_t)img * P + p) * 4;
        const float* pp = priors + (size_t)p * 4;
        float cx = lp[0] * 0.1f * pp[2] + pp[0];
        float cy = lp[1] * 0.1f * pp[3] + pp[1];
        float w = expf(lp[2] * 0.2f) * pp[2];
        float h = expf(lp[3] * 0.2f) * pp[3];
        x1[tid] = (cx - w * 0.5f) * IMG_SZ;
        y1[tid] = (cy - h * 0.5f) * IMG_SZ;
        x2[tid] = (cx + w * 0.5f) * IMG_SZ;
        y2[tid] = (cy + h * 0.5f) * IMG_SZ;
        scs[tid] = v[tid];
        lab[tid] = c;
    }
    __syncthreads();

    float m = -INFINITY;
    if (tid < NCAND) m = fmaxf(fmaxf(x1[tid], y1[tid]), fmaxf(x2[tid], y2[tid]));
#pragma unroll
    for (int off = 32; off >= 1; off >>= 1) m = fmaxf(m, __shfl_xor(m, off));
    if (lane == 0) wred[wv] = m;
    __syncthreads();
    if (tid == 0) {
        float mm = -INFINITY;
        for (int t = 0; t < 8; ++t) mm = fmaxf(mm, wred[t]);
        maxc_sh = mm;
    }
    __syncthreads();

    if (tid < NPAD) {
        if (tid < NCAND) {
            float off = (float)lab[tid] * (maxc_sh + 1.0f);
            ox1[tid] = x1[tid] + off;
            oy1[tid] = y1[tid] + off;
            ox2[tid] = x2[tid] + off;
            oy2[tid] = y2[tid] + off;
            areas[tid] = (ox2[tid] - ox1[tid]) * (oy2[tid] - oy1[tid]);
        } else {
            ox1[tid] = 1e30f; oy1[tid] = 1e30f;
            ox2[tid] = 1e30f; oy2[tid] = 1e30f;
            areas[tid] = 0.0f;
        }
    }
    __syncthreads();

    // IoU mask rows via ballot (8 waves)
    for (int i = wv; i < NCAND; i += 8) {
        float a1 = ox1[i], b1 = oy1[i], a2 = ox2[i], b2 = oy2[i], ar = areas[i];
#pragma unroll
        for (int wd = 0; wd < NWORDS; ++wd) {
            int j = wd * 64 + lane;
            float iw_ = fmaxf(fminf(a2, ox2[j]) - fmaxf(a1, ox1[j]), 0.0f);
            float ih_ = fmaxf(fminf(b2, oy2[j]) - fmaxf(b1, oy1[j]), 0.0f);
            float inter = iw_ * ih_;
            float uni = ar + areas[j] - inter;
            float iou = inter / fmaxf(uni, 1e-12f);
            unsigned long long bits = __ballot(iou > NMS_THR);
            if (lane == 0) M[i][wd] = bits;
        }
    }
    __syncthreads();

    // greedy NMS: wave 0, rows distributed across lanes, SALU serial core
    if (wv == 0) {
        unsigned long long acc[NWORDS] = {0, 0, 0, 0, 0, 0, 0};
        unsigned long long keepw[NWORDS];
#pragma unroll
        for (int iw = 0; iw < NWORDS; ++iw) {
            unsigned long long mrow[NWORDS];
#pragma unroll
            for (int w = 0; w < NWORDS; ++w) mrow[w] = M[iw * 64 + lane][w];
            unsigned long long sup = acc[iw];
            unsigned long long K = 0;
            int nb = (iw == NWORDS - 1) ? (NCAND - 64 * (NWORDS - 1)) : 64;
            for (int ib = 0; ib < nb; ++ib) {
                if (!((sup >> ib) & 1ull)) {
                    K |= (1ull << ib);
                    sup |= rdlane64(mrow[iw], ib);
#pragma unroll
                    for (int w = 0; w < NWORDS; ++w) acc[w] |= rdlane64(mrow[w], ib);
                }
            }
            keepw[iw] = K;
        }
        if (lane == 0) {
            int a = 0;
#pragma unroll
            for (int w = 0; w < NWORDS; ++w) {
                keepw_s[w] = keepw[w];
                wpre_s[w] = a;
                a += __popcll(keepw[w]);
            }
            wpre_s[NWORDS] = a;
        }
    }
    __syncthreads();

    // kidx: kept (ascending) then unkept (ascending)
    if (tid < NCAND) {
        int w = tid >> 6, b = tid & 63;
        unsigned long long kwv = keepw_s[w];
        bool kp = (kwv >> b) & 1ull;
        unsigned long long below_mask = (b == 0) ? 0ull : (~0ull >> (64 - b));
        int below = wpre_s[w] + __popcll(kwv & below_mask);
        int nkept = wpre_s[NWORDS];
        int pos = kp ? below : nkept + (tid - below);
        if (pos < NOUT) kidx[pos] = tid;
    }
    __syncthreads();

    if (tid < NOUT) {
        int i = kidx[tid];
        bool kp = (keepw_s[i >> 6] >> (i & 63)) & 1ull;
        float* ob = out + ((size_t)img * NOUT + tid) * 4;
        ob[0] = x1[i];
        ob[1] = y1[i];
        ob[2] = x2[i];
        ob[3] = y2[i];
        out[(size_t)BATCH * NOUT * 4 + (size_t)img * NOUT + tid] = (float)lab[i];
        out[(size_t)BATCH * NOUT * 4 + (size_t)BATCH * NOUT + (size_t)img * NOUT + tid] =
            kp ? scs[i] : -INFINITY;
    }
}

extern "C" void kernel_launch(void* const* d_in, const int* in_sizes, int n_in,
                              void* d_out, int out_size, void* d_ws, size_t ws_size,
                              hipStream_t stream) {
    const float* logits = (const float*)d_in[0];
    const float* bbox = (const float*)d_in[1];
    const float* priors = (const float*)d_in[2];
    float* out = (float*)d_out;
    char* ws = (char*)d_ws;

    unsigned* hist = (unsigned*)(ws + OFF_HIST);
    unsigned* cnt = (unsigned*)(ws + OFF_CNT);
    unsigned* thr = (unsigned*)(ws + OFF_THR);
    float* cval = (float*)(ws + OFF_CVAL);
    unsigned* cidx = (unsigned*)(ws + OFF_CIDX);
    float* maxsc = (float*)(ws + OFF_MAXSC);

    int fast = (ws_size >= NEED_FAST) ? 1 : 0;

    hipMemsetAsync(ws, 0, OFF_CVAL, stream);  // hist + cnt + thr

    dim3 g1(P / TROWS, BATCH);
    k_hist<<<g1, TROWS, 0, stream>>>(logits, hist, fast ? maxsc : (float*)ws, fast);
    k_thresh<<<BATCH, NBINS, 0, stream>>>(hist, thr);
    if (fast) {
        dim3 g2(P / 256, BATCH);
        k_collect_fast<<<g2, 256, 0, stream>>>(logits, maxsc, thr, cnt, cval, cidx);
    } else {
        k_collect_full<<<g1, TROWS, 0, stream>>>(logits, thr, cnt, cval, cidx);
    }
    k_nms<<<BATCH, 512, 0, stream>>>(bbox, priors, cnt, cval, cidx, out);
}

// Round 4
// 417.629 us; speedup vs baseline: 1.7889x; 1.1993x over previous
//
#include <hip/hip_runtime.h>
#include <math.h>

#define BATCH 16
#define P 32768
#define C 81
#define CM1 80
#define NCAND 400
#define NOUT 100
#define NBINS 256
#define SMIN_F (-3.0f)
#define BIN_SCALE (NBINS / 3.0f)
#define CAND_MAX 4096
#define SORTN 1024
#define IMG_SZ 512.0f
#define NMS_THR 0.45f
#define NWORDS 7
#define NPAD 448

// ---- workspace layout (bytes) ----
#define OFF_HIST 0                                   // BATCH*NBINS*4 = 16384
#define OFF_CNT  (OFF_HIST + BATCH * NBINS * 4)      // 64
#define OFF_CVAL (OFF_CNT + 128)                     // BATCH*CAND_MAX*4
#define OFF_CIDX (OFF_CVAL + BATCH * CAND_MAX * 4)
#define OFF_MAXSC (OFF_CIDX + BATCH * CAND_MAX * 4)  // BATCH*P*4 = 2 MB
#define NEED_FAST (OFF_MAXSC + (size_t)BATCH * P * 4)

__device__ __forceinline__ int score_bin(float sc) {
    int b = (int)((sc - SMIN_F) * BIN_SCALE);
    return b < 0 ? 0 : (b > NBINS - 1 ? NBINS - 1 : b);
}

// Quad-per-row stats. MUST be bit-identical between k_hist and k_collect:
// lane q of a 4-lane quad holds columns c = 4k+q, reductions via xor-1/xor-2.
__device__ __forceinline__ void quad_stats(const float* __restrict__ rowp, int q,
                                           float r[21], float& m, float& l, float& fg) {
#pragma unroll
    for (int k = 0; k < 21; ++k) {
        int c = 4 * k + q;
        r[k] = (c < C) ? rowp[c] : -INFINITY;
    }
    float mm = -INFINITY;
#pragma unroll
    for (int k = 0; k < 21; ++k) mm = fmaxf(mm, r[k]);
    mm = fmaxf(mm, __shfl_xor(mm, 1));
    mm = fmaxf(mm, __shfl_xor(mm, 2));
    float s = 0.0f;
#pragma unroll
    for (int k = 0; k < 21; ++k) {
        int c = 4 * k + q;
        if (c < C) s += __expf(r[k] - mm);
    }
    s += __shfl_xor(s, 1);
    s += __shfl_xor(s, 2);
    float fgm = -INFINITY;
#pragma unroll
    for (int k = 0; k < 21; ++k) {
        int c = 4 * k + q;
        if (c >= 1 && c < C) fgm = fmaxf(fgm, r[k]);
    }
    fgm = fmaxf(fgm, __shfl_xor(fgm, 1));
    fgm = fmaxf(fgm, __shfl_xor(fgm, 2));
    m = mm;
    l = __logf(s);
    fg = fgm;
}

__global__ __launch_bounds__(256) void k_hist(const float* __restrict__ logits,
                                              unsigned* __restrict__ hist,
                                              float* __restrict__ maxsc,
                                              int write_maxsc) {
    __shared__ unsigned lh[NBINS];
    lh[threadIdx.x] = 0;
    __syncthreads();
    int img = blockIdx.y;
    int quad = threadIdx.x >> 2, q = threadIdx.x & 3;
    int row = blockIdx.x * 64 + quad;
    const float* rowp = logits + ((size_t)img * P + row) * C;
    float r[21], m, l, fg;
    quad_stats(rowp, q, r, m, l, fg);
    if (write_maxsc && q == 0) maxsc[(size_t)img * P + row] = (fg - m) - l;
#pragma unroll
    for (int k = 0; k < 21; ++k) {
        int c = 4 * k + q;
        if (c >= 1 && c < C) {
            float sc = (r[k] - m) - l;
            if (sc > SMIN_F) atomicAdd(&lh[score_bin(sc)], 1u);
        }
    }
    __syncthreads();
    unsigned h = lh[threadIdx.x];
    if (h) atomicAdd(&hist[(size_t)img * NBINS + threadIdx.x], h);
}

__global__ __launch_bounds__(256) void k_collect(const float* __restrict__ logits,
                                                 const unsigned* __restrict__ hist,
                                                 const float* __restrict__ maxsc,
                                                 int use_maxsc,
                                                 unsigned* __restrict__ cnt,
                                                 float* __restrict__ cval,
                                                 unsigned* __restrict__ cidx) {
    __shared__ unsigned sh[NBINS];
    __shared__ int tb_sh;
    int img = blockIdx.y;
    int b = threadIdx.x;
    sh[b] = hist[(size_t)img * NBINS + b];
    if (b == 0) tb_sh = 0;
    __syncthreads();
    // inclusive suffix sum (8 log-steps)
#pragma unroll
    for (int st = 1; st < NBINS; st <<= 1) {
        unsigned v = sh[b] + ((b + st < NBINS) ? sh[b + st] : 0u);
        __syncthreads();
        sh[b] = v;
        __syncthreads();
    }
    if (sh[b] >= NCAND) atomicMax(&tb_sh, b);
    __syncthreads();
    int tb = tb_sh;

    int quad = threadIdx.x >> 2, q = threadIdx.x & 3;
    int row = blockIdx.x * 64 + quad;
    bool qual = true;
    if (use_maxsc) {
        float ms = maxsc[(size_t)img * P + row];
        qual = (ms > SMIN_F) && (score_bin(ms) >= tb);
    }
    if (qual) {
        const float* rowp = logits + ((size_t)img * P + row) * C;
        float r[21], m, l, fg;
        quad_stats(rowp, q, r, m, l, fg);
#pragma unroll
        for (int k = 0; k < 21; ++k) {
            int c = 4 * k + q;
            if (c >= 1 && c < C) {
                float sc = (r[k] - m) - l;
                if (sc > SMIN_F && score_bin(sc) >= tb) {
                    unsigned pos = atomicAdd(&cnt[img], 1u);
                    if (pos < CAND_MAX) {
                        cval[(size_t)img * CAND_MAX + pos] = sc;
                        cidx[(size_t)img * CAND_MAX + pos] = (unsigned)(row * CM1 + c - 1);
                    }
                }
            }
        }
    }
}

__device__ __forceinline__ unsigned long long rdlane64(unsigned long long v, int lane) {
    int lo = __builtin_amdgcn_readlane((int)(unsigned)v, lane);
    int hi = __builtin_amdgcn_readlane((int)(unsigned)(v >> 32), lane);
    return ((unsigned long long)(unsigned)hi << 32) | (unsigned)lo;
}

__global__ __launch_bounds__(1024) void k_nms(const float* __restrict__ bbox,
                                              const float* __restrict__ priors,
                                              const unsigned* __restrict__ cnt,
                                              const float* __restrict__ cval,
                                              const unsigned* __restrict__ cidx,
                                              float* __restrict__ out) {
    __shared__ unsigned long long key[SORTN];
    __shared__ float x1[NCAND], y1[NCAND], x2[NCAND], y2[NCAND];
    __shared__ float ox1[NPAD], oy1[NPAD], ox2[NPAD], oy2[NPAD], areas[NPAD];
    __shared__ float scs[NCAND];
    __shared__ int lab[NCAND];
    __shared__ unsigned long long M[NPAD][NWORDS];
    __shared__ unsigned long long keepw_s[NWORDS];
    __shared__ int wpre_s[NWORDS + 1];
    __shared__ float wred[16];
    __shared__ float maxc_sh;
    __shared__ int kidx[NOUT];

    int img = blockIdx.x;
    int tid = threadIdx.x;
    int lane = tid & 63;
    int wv = tid >> 6;

    unsigned n = cnt[img];
    if (n > SORTN) n = SORTN;
    {
        float v;
        unsigned id;
        if ((unsigned)tid < n) {
            v = cval[(size_t)img * CAND_MAX + tid];
            id = cidx[(size_t)img * CAND_MAX + tid];
        } else {
            v = -INFINITY;
            id = 0x7FFFFFFFu;
        }
        unsigned bits = __float_as_uint(v);
        unsigned u = (bits & 0x80000000u) ? ~bits : (bits | 0x80000000u);  // ascending map
        key[tid] = ((unsigned long long)(~u) << 32) | id;  // ascending key == desc value, asc idx
    }
    __syncthreads();

    // bitonic sort ascending on u64 keys
    for (int k2 = 2; k2 <= SORTN; k2 <<= 1) {
        for (int j = k2 >> 1; j > 0; j >>= 1) {
            int l = tid ^ j;
            if (l > tid) {
                unsigned long long a = key[tid], bb = key[l];
                bool up = ((tid & k2) == 0);
                if ((a > bb) == up) { key[tid] = bb; key[l] = a; }
            }
            __syncthreads();
        }
    }

    // decode top-400
    if (tid < NCAND) {
        unsigned long long kk = key[tid];
        unsigned uu = ~(unsigned)(kk >> 32);
        unsigned bits = (uu & 0x80000000u) ? (uu & 0x7FFFFFFFu) : ~uu;
        scs[tid] = __uint_as_float(bits);
        unsigned f = (unsigned)(kk & 0xFFFFFFFFu);
        if (f > (unsigned)(P * CM1 - 1)) f = (unsigned)(P * CM1 - 1);
        int p = (int)(f / CM1);
        int c = (int)(f % CM1) + 1;
        const float* lp = bbox + ((size_t)img * P + p) * 4;
        const float* pp = priors + (size_t)p * 4;
        float cx = lp[0] * 0.1f * pp[2] + pp[0];
        float cy = lp[1] * 0.1f * pp[3] + pp[1];
        float w = expf(lp[2] * 0.2f) * pp[2];
        float h = expf(lp[3] * 0.2f) * pp[3];
        x1[tid] = (cx - w * 0.5f) * IMG_SZ;
        y1[tid] = (cy - h * 0.5f) * IMG_SZ;
        x2[tid] = (cx + w * 0.5f) * IMG_SZ;
        y2[tid] = (cy + h * 0.5f) * IMG_SZ;
        lab[tid] = c;
    }
    __syncthreads();

    float m = -INFINITY;
    if (tid < NCAND) m = fmaxf(fmaxf(x1[tid], y1[tid]), fmaxf(x2[tid], y2[tid]));
#pragma unroll
    for (int off = 32; off >= 1; off >>= 1) m = fmaxf(m, __shfl_xor(m, off));
    if (lane == 0) wred[wv] = m;
    __syncthreads();
    if (tid == 0) {
        float mm = -INFINITY;
        for (int t = 0; t < 16; ++t) mm = fmaxf(mm, wred[t]);
        maxc_sh = mm;
    }
    __syncthreads();

    if (tid < NPAD) {
        if (tid < NCAND) {
            float off = (float)lab[tid] * (maxc_sh + 1.0f);
            ox1[tid] = x1[tid] + off;
            oy1[tid] = y1[tid] + off;
            ox2[tid] = x2[tid] + off;
            oy2[tid] = y2[tid] + off;
            areas[tid] = (ox2[tid] - ox1[tid]) * (oy2[tid] - oy1[tid]);
        } else {
            ox1[tid] = 1e30f; oy1[tid] = 1e30f;
            ox2[tid] = 1e30f; oy2[tid] = 1e30f;
            areas[tid] = 0.0f;
        }
    }
    __syncthreads();

    // IoU mask rows via ballot (16 waves)
    for (int i = wv; i < NCAND; i += 16) {
        float a1 = ox1[i], b1 = oy1[i], a2 = ox2[i], b2 = oy2[i], ar = areas[i];
#pragma unroll
        for (int wd = 0; wd < NWORDS; ++wd) {
            int j = wd * 64 + lane;
            float iw_ = fmaxf(fminf(a2, ox2[j]) - fmaxf(a1, ox1[j]), 0.0f);
            float ih_ = fmaxf(fminf(b2, oy2[j]) - fmaxf(b1, oy1[j]), 0.0f);
            float inter = iw_ * ih_;
            float uni = ar + areas[j] - inter;
            float iou = inter / fmaxf(uni, 1e-12f);
            unsigned long long bits = __ballot(iou > NMS_THR);
            if (lane == 0) M[i][wd] = bits;
        }
    }
    __syncthreads();

    // greedy NMS: wave 0, M rows pre-distributed across lanes, readlane serial core
    if (wv == 0) {
        unsigned long long acc[NWORDS] = {0, 0, 0, 0, 0, 0, 0};
        unsigned long long keepw[NWORDS];
#pragma unroll
        for (int iw = 0; iw < NWORDS; ++iw) {
            unsigned long long mrow[NWORDS];
#pragma unroll
            for (int w = 0; w < NWORDS; ++w) mrow[w] = M[iw * 64 + lane][w];
            unsigned long long sup = acc[iw];
            unsigned long long K = 0;
            int nb = (iw == NWORDS - 1) ? (NCAND - 64 * (NWORDS - 1)) : 64;
            for (int ib = 0; ib < nb; ++ib) {
                if (!((sup >> ib) & 1ull)) {
                    K |= (1ull << ib);
                    sup |= rdlane64(mrow[iw], ib);
#pragma unroll
                    for (int w = 0; w < NWORDS; ++w) acc[w] |= rdlane64(mrow[w], ib);
                }
            }
            keepw[iw] = K;
        }
        if (lane == 0) {
            int a = 0;
#pragma unroll
            for (int w = 0; w < NWORDS; ++w) {
                keepw_s[w] = keepw[w];
                wpre_s[w] = a;
                a += __popcll(keepw[w]);
            }
            wpre_s[NWORDS] = a;
        }
    }
    __syncthreads();

    // kidx: kept (ascending) then unkept (ascending)
    if (tid < NCAND) {
        int w = tid >> 6, bb = tid & 63;
        unsigned long long kwv = keepw_s[w];
        bool kp = (kwv >> bb) & 1ull;
        unsigned long long below_mask = (bb == 0) ? 0ull : (~0ull >> (64 - bb));
        int below = wpre_s[w] + __popcll(kwv & below_mask);
        int nkept = wpre_s[NWORDS];
        int pos = kp ? below : nkept + (tid - below);
        if (pos < NOUT) kidx[pos] = tid;
    }
    __syncthreads();

    if (tid < NOUT) {
        int i = kidx[tid];
        bool kp = (keepw_s[i >> 6] >> (i & 63)) & 1ull;
        float* ob = out + ((size_t)img * NOUT + tid) * 4;
        ob[0] = x1[i];
        ob[1] = y1[i];
        ob[2] = x2[i];
        ob[3] = y2[i];
        out[(size_t)BATCH * NOUT * 4 + (size_t)img * NOUT + tid] = (float)lab[i];
        out[(size_t)BATCH * NOUT * 4 + (size_t)BATCH * NOUT + (size_t)img * NOUT + tid] =
            kp ? scs[i] : -INFINITY;
    }
}

extern "C" void kernel_launch(void* const* d_in, const int* in_sizes, int n_in,
                              void* d_out, int out_size, void* d_ws, size_t ws_size,
                              hipStream_t stream) {
    const float* logits = (const float*)d_in[0];
    const float* bbox = (const float*)d_in[1];
    const float* priors = (const float*)d_in[2];
    float* out = (float*)d_out;
    char* ws = (char*)d_ws;

    unsigned* hist = (unsigned*)(ws + OFF_HIST);
    unsigned* cnt = (unsigned*)(ws + OFF_CNT);
    float* cval = (float*)(ws + OFF_CVAL);
    unsigned* cidx = (unsigned*)(ws + OFF_CIDX);
    float* maxsc = (float*)(ws + OFF_MAXSC);

    int fast = (ws_size >= NEED_FAST) ? 1 : 0;

    hipMemsetAsync(ws, 0, OFF_CVAL, stream);  // hist + cnt

    dim3 g1(P / 64, BATCH);
    k_hist<<<g1, 256, 0, stream>>>(logits, hist, fast ? maxsc : (float*)ws, fast);
    k_collect<<<g1, 256, 0, stream>>>(logits, hist, maxsc, fast, cnt, cval, cidx);
    k_nms<<<BATCH, 1024, 0, stream>>>(bbox, priors, cnt, cval, cidx, out);
}